// Round 1
// baseline (133.598 us; speedup 1.0000x reference)
//
#include <hip/hip_runtime.h>
#include <cmath>

#define B_LEN 8
#define S_LEN 16384
#define D_LEN 512
#define K0 32
#define K1 64
#define KTOT 96
#define ROWS 192          // output rows per b: 32 mean0, 32 var0, 64 mean1, 64 var1
#define NCHUNK 256
#define SC (S_LEN / NCHUNK)

// ws layout: p[96] floats at [0..95], q[96] floats at [96..191]
__global__ void vp_boundaries(const float* __restrict__ s0,
                              const float* __restrict__ s1,
                              float* __restrict__ pq) {
    if (threadIdx.x != 0 || blockIdx.x != 0) return;
    double e[64];
    // ---- set 0 (K0 segments) ----
    {
        double m = -1e300;
        for (int k = 0; k < K0; ++k) m = fmax(m, (double)s0[k] * 10.0);
        double sum = 0.0;
        for (int k = 0; k < K0; ++k) { e[k] = exp((double)s0[k] * 10.0 - m); sum += e[k]; }
        double c = 0.0;
        for (int k = 0; k < K0; ++k) {
            float p = (float)(c * (double)S_LEN);
            c += e[k] / sum;
            float q = fminf((float)(c * (double)S_LEN), (float)S_LEN - 0.01f);
            pq[k] = p;
            pq[KTOT + k] = q;
        }
    }
    // ---- set 1 (K1 segments) ----
    {
        double m = -1e300;
        for (int k = 0; k < K1; ++k) m = fmax(m, (double)s1[k] * 10.0);
        double sum = 0.0;
        for (int k = 0; k < K1; ++k) { e[k] = exp((double)s1[k] * 10.0 - m); sum += e[k]; }
        double c = 0.0;
        for (int k = 0; k < K1; ++k) {
            float p = (float)(c * (double)S_LEN);
            c += e[k] / sum;
            float q = fminf((float)(c * (double)S_LEN), (float)S_LEN - 0.01f);
            pq[K0 + k] = p;
            pq[KTOT + K0 + k] = q;
        }
    }
}

// Streaming pass: one read of x; accumulate sx (into mean slots) and sx2 (into
// var slots) of d_out via atomicAdd. d_out must be zeroed beforehand.
__global__ __launch_bounds__(128) void vp_main(const float* __restrict__ x,
                                               const float* __restrict__ pq,
                                               float* __restrict__ out) {
    const int chunk = blockIdx.x;
    const int b     = blockIdx.y;
    const int d     = threadIdx.x << 2;          // 4 consecutive d per thread
    const int s_begin = chunk * SC;
    const int s_end   = s_begin + SC;
    const float fsb = (float)s_begin;

    // initial segment index per set: smallest k with q[k] > s_begin
    int k0 = 0; while (k0 < K0 && pq[KTOT + k0] <= fsb) ++k0;
    int k1 = 0; while (k1 < K1 && pq[KTOT + K0 + k1] <= fsb) ++k1;
    float p0 = 0.f, q0 = 0.f, p1 = 0.f, q1 = 0.f;
    if (k0 < K0) { p0 = pq[k0];      q0 = pq[KTOT + k0]; }
    if (k1 < K1) { p1 = pq[K0 + k1]; q1 = pq[KTOT + K0 + k1]; }

    // accumulators: a = sum(w*x), c = sum(w*x*x), per set, 4 lanes of d
    float a0x=0.f,a0y=0.f,a0z=0.f,a0w=0.f, c0x=0.f,c0y=0.f,c0z=0.f,c0w=0.f;
    float a1x=0.f,a1y=0.f,a1z=0.f,a1w=0.f, c1x=0.f,c1y=0.f,c1z=0.f,c1w=0.f;

    const float* xb = x + (size_t)b * S_LEN * D_LEN + d;
    float* ob = out + (size_t)b * ROWS * D_LEN + d;

#define FLUSH(MROW, VROW, ax,ay,az,aw, cx,cy,cz,cw) do {                     \
    float* mp_ = ob + (size_t)(MROW) * D_LEN;                                \
    float* vp_ = ob + (size_t)(VROW) * D_LEN;                                \
    atomicAdd(mp_+0, ax); atomicAdd(mp_+1, ay);                              \
    atomicAdd(mp_+2, az); atomicAdd(mp_+3, aw);                              \
    atomicAdd(vp_+0, cx); atomicAdd(vp_+1, cy);                              \
    atomicAdd(vp_+2, cz); atomicAdd(vp_+3, cw);                              \
    ax=0.f;ay=0.f;az=0.f;aw=0.f;cx=0.f;cy=0.f;cz=0.f;cw=0.f; } while (0)

    for (int s = s_begin; s < s_end; ++s) {
        const float4 xv = *(const float4*)(xb + (size_t)s * D_LEN);
        const float xx = xv.x*xv.x, xy = xv.y*xv.y, xz = xv.z*xv.z, xw = xv.w*xv.w;
        const float fs = (float)s, fs1 = fs + 1.0f;

        // ---- set 0 ----
        while (k0 < K0 && q0 <= fs1) {        // segment ends inside [s, s+1)
            const float w = fmaxf(q0 - fmaxf(p0, fs), 0.f);
            a0x += w*xv.x; a0y += w*xv.y; a0z += w*xv.z; a0w += w*xv.w;
            c0x += w*xx;   c0y += w*xy;   c0z += w*xz;   c0w += w*xw;
            FLUSH(k0, K0 + k0, a0x,a0y,a0z,a0w, c0x,c0y,c0z,c0w);
            ++k0;
            if (k0 < K0) { p0 = pq[k0]; q0 = pq[KTOT + k0]; }
        }
        if (k0 < K0) {                        // segment continues past s+1
            const float w = fmaxf(fs1 - fmaxf(p0, fs), 0.f);
            a0x += w*xv.x; a0y += w*xv.y; a0z += w*xv.z; a0w += w*xv.w;
            c0x += w*xx;   c0y += w*xy;   c0z += w*xz;   c0w += w*xw;
        }

        // ---- set 1 ----
        while (k1 < K1 && q1 <= fs1) {
            const float w = fmaxf(q1 - fmaxf(p1, fs), 0.f);
            a1x += w*xv.x; a1y += w*xv.y; a1z += w*xv.z; a1w += w*xv.w;
            c1x += w*xx;   c1y += w*xy;   c1z += w*xz;   c1w += w*xw;
            FLUSH(64 + k1, 128 + k1, a1x,a1y,a1z,a1w, c1x,c1y,c1z,c1w);
            ++k1;
            if (k1 < K1) { p1 = pq[K0 + k1]; q1 = pq[KTOT + K0 + k1]; }
        }
        if (k1 < K1) {
            const float w = fmaxf(fs1 - fmaxf(p1, fs), 0.f);
            a1x += w*xv.x; a1y += w*xv.y; a1z += w*xv.z; a1w += w*xv.w;
            c1x += w*xx;   c1y += w*xy;   c1z += w*xz;   c1w += w*xw;
        }
    }

    // residual flush: current segments continue into the next chunk
    if (k0 < K0) FLUSH(k0, K0 + k0, a0x,a0y,a0z,a0w, c0x,c0y,c0z,c0w);
    if (k1 < K1) FLUSH(64 + k1, 128 + k1, a1x,a1y,a1z,a1w, c1x,c1y,c1z,c1w);
#undef FLUSH
}

// In-place: mean slot holds sx, var slot holds sx2 -> convert to mean / std.
__global__ void vp_finalize(const float* __restrict__ pq, float* __restrict__ out) {
    const int idx = blockIdx.x * blockDim.x + threadIdx.x;
    if (idx >= B_LEN * KTOT * D_LEN) return;
    const int d = idx % D_LEN;
    const int t = idx / D_LEN;
    const int k = t % KTOT;
    const int b = t / KTOT;

    const float p = pq[k];
    const float q = pq[KTOT + k];
    const float denom = q - p;

    int meanrow, varrow;
    if (k < K0) { meanrow = k;              varrow = K0 + k;         }
    else        { meanrow = 64 + (k - K0);  varrow = 128 + (k - K0); }

    float* ob = out + (size_t)b * ROWS * D_LEN;
    const float sx  = ob[(size_t)meanrow * D_LEN + d];
    const float sx2 = ob[(size_t)varrow  * D_LEN + d];
    const float mean = sx / denom;
    const float stdv = sqrtf(fmaxf(sx2 - mean * mean * denom, 0.f) / denom);
    ob[(size_t)meanrow * D_LEN + d] = mean;
    ob[(size_t)varrow  * D_LEN + d] = stdv;
}

extern "C" void kernel_launch(void* const* d_in, const int* in_sizes, int n_in,
                              void* d_out, int out_size, void* d_ws, size_t ws_size,
                              hipStream_t stream) {
    const float* x  = (const float*)d_in[0];
    const float* s0 = (const float*)d_in[1];
    const float* s1 = (const float*)d_in[2];
    float* out = (float*)d_out;
    float* pq  = (float*)d_ws;   // 192 floats

    hipMemsetAsync(d_out, 0, (size_t)out_size * sizeof(float), stream);
    vp_boundaries<<<1, 64, 0, stream>>>(s0, s1, pq);

    dim3 grid(NCHUNK, B_LEN);
    vp_main<<<grid, 128, 0, stream>>>(x, pq, out);

    const int total = B_LEN * KTOT * D_LEN;
    vp_finalize<<<(total + 255) / 256, 256, 0, stream>>>(pq, out);
}